// Round 5
// baseline (164.145 us; speedup 1.0000x reference)
//
#include <hip/hip_runtime.h>
#include <math.h>

#define NH 16
#define HD 64
#define SEQ 2048
#define BAT 2
#define EMB 1024
#define MTOT (BAT*SEQ)   // 4096
#define NTOT (3*EMB)     // 3072

typedef __attribute__((ext_vector_type(8))) short bf16x8;
typedef __attribute__((ext_vector_type(4))) float f32x4;

#define MFMA16(a,b,c) __builtin_amdgcn_mfma_f32_16x16x32_bf16(a,b,c,0,0,0)

__device__ inline short f2bf(float f) {
    union { float f; unsigned u; } x; x.f = f;
    unsigned r = (x.u + 0x7FFF + ((x.u >> 16) & 1)) >> 16;
    return (short)r;
}

// raw v_exp_f32 (inputs bounded to [-12,12]: no range/denorm handling needed)
__device__ inline float fast_exp2(float x) {
#if __has_builtin(__builtin_amdgcn_exp2f)
    return __builtin_amdgcn_exp2f(x);
#else
    float r; asm("v_exp_f32 %0, %1" : "=v"(r) : "v"(x)); return r;
#endif
}

// pack two rounded bf16 into one dword: 2x v_add + 1x v_perm
__device__ inline unsigned pack2bf(float a, float b) {
    union { float f; unsigned u; } x, y; x.f = a; y.f = b;
    return __builtin_amdgcn_perm(y.u + 0x8000u, x.u + 0x8000u, 0x07060302u);
}

typedef const __attribute__((address_space(1))) void* gp_t;
typedef __attribute__((address_space(3))) void* lp_t;
// async global->LDS, 16B/lane; LDS dest = wave-uniform base + lane*16
__device__ inline void gload16(const void* g, void* l) {
    __builtin_amdgcn_global_load_lds((gp_t)(uintptr_t)g, (lp_t)(uintptr_t)l, 16, 0, 0);
}

// ---------------------------------------------------------------------------
// Prep: f32 -> bf16 for X (4M) and Wq|Wk|Wv (3M) into scratch carved from d_out.
// ---------------------------------------------------------------------------
__global__ __launch_bounds__(256) void prep_kernel(
    const float* __restrict__ x, const float* __restrict__ wq,
    const float* __restrict__ wk, const float* __restrict__ wv,
    short* __restrict__ xb, short* __restrict__ wb)
{
    const size_t NX = (size_t)MTOT * EMB;
    const size_t NW = (size_t)EMB * EMB;
    const size_t i4 = ((size_t)blockIdx.x * 256 + threadIdx.x) * 4;
    float4 v; short* dst;
    if (i4 < NX) { v = *(const float4*)(x + i4); dst = xb + i4; }
    else {
        size_t j = i4 - NX;
        const float* s = (j < NW) ? wq : (j < 2 * NW) ? wk : wv;
        v = *(const float4*)(s + (j & (NW - 1)));
        dst = wb + j;
    }
    short4 o; o.x = f2bf(v.x); o.y = f2bf(v.y); o.z = f2bf(v.z); o.w = f2bf(v.w);
    *(short4*)dst = o;
}

// ---------------------------------------------------------------------------
// Fused QKV GEMM (m97 structure): 128x128 tile, BK=64, global_load_lds w=16,
// XOR-swizzled LDS. 1-D grid with XCD-locality swizzle: each XCD owns a
// 4-m-tile A-strip (1 MB, L2-resident) x all 24 n-tiles.
// Epilogue: Q l2norm*(g*log2e), K l2norm -> [bh][s][d];
// V transposed+permuted -> vperm[bh][d][pos(s)].
// ---------------------------------------------------------------------------
__global__ __launch_bounds__(256) void qkv_gemm_fast(
    const short* __restrict__ xb, const short* __restrict__ wb,
    short* __restrict__ qws, short* __restrict__ kws, short* __restrict__ vperm,
    const float* __restrict__ gptr)
{
    __shared__ short As[128 * 64];
    __shared__ short Bs[128 * 64];
    const int id = blockIdx.x;
    const int xcd = id & 7, q8 = id >> 3;           // HW round-robins id%8 -> XCD
    const int m0 = (xcd * 4 + (q8 & 3)) * 128;      // 4 m-tiles per XCD
    const int n0 = (q8 >> 2) * 128;                 // 24 n-tiles swept per XCD
    const int t = threadIdx.x, wave = t >> 6, lane = t & 63;
    const int quad = lane >> 4, l16 = lane & 15;
    const int wm = (wave & 1) * 64, wn = (wave >> 1) * 64;

    // staging decode: instr j covers LDS rows wave*32+j*8 .. +7
    const int srow = wave * 32 + (lane >> 3);
    const int scol = ((lane & 7) ^ (srow & 7)) * 8;
    const short* ga = xb + (size_t)(m0 + srow) * EMB + scol;
    const short* gb = wb + (size_t)(n0 + srow) * EMB + scol;
    short* lA = As + (size_t)wave * 2048;
    short* lB = Bs + (size_t)wave * 2048;

    const short* Aa[2]; const short* Ba[2];
#pragma unroll
    for (int ks = 0; ks < 2; ++ks) {
        const int pc = (ks * 32 + quad * 8) ^ ((l16 & 7) * 8);
        Aa[ks] = As + (wm + l16) * 64 + pc;
        Ba[ks] = Bs + (wn + l16) * 64 + pc;
    }

    f32x4 acc[4][4] = {};

    for (int k0 = 0; k0 < EMB; k0 += 64) {
#pragma unroll
        for (int j = 0; j < 4; ++j) {
            gload16(ga + k0 + (size_t)j * 8 * EMB, lA + j * 512);
            gload16(gb + k0 + (size_t)j * 8 * EMB, lB + j * 512);
        }
        __syncthreads();
#pragma unroll
        for (int ks = 0; ks < 2; ++ks) {
            bf16x8 af[4], bfr[4];
#pragma unroll
            for (int i = 0; i < 4; ++i) af[i]  = *(const bf16x8*)(Aa[ks] + i * 1024);
#pragma unroll
            for (int i = 0; i < 4; ++i) bfr[i] = *(const bf16x8*)(Ba[ks] + i * 1024);
#pragma unroll
            for (int mf = 0; mf < 4; ++mf)
#pragma unroll
                for (int nf = 0; nf < 4; ++nf)
                    acc[mf][nf] = MFMA16(af[mf], bfr[nf], acc[mf][nf]);
        }
        __syncthreads();
    }

    // ---- epilogue ----
    const int mat = n0 >> 10;   // 0=Q,1=K,2=V (block-uniform)
    if (mat < 2) {
        const float scale = (mat == 0) ? gptr[0] * 1.4426950408889634f : 1.0f;
        float inv[4][4];
#pragma unroll
        for (int mf = 0; mf < 4; ++mf)
#pragma unroll
            for (int reg = 0; reg < 4; ++reg) {
                float ss = 0.f;
#pragma unroll
                for (int nf = 0; nf < 4; ++nf) { float v = acc[mf][nf][reg]; ss += v * v; }
                ss += __shfl_xor(ss, 1, 16);
                ss += __shfl_xor(ss, 2, 16);
                ss += __shfl_xor(ss, 4, 16);
                ss += __shfl_xor(ss, 8, 16);
                inv[mf][reg] = scale / fmaxf(sqrtf(ss), 1e-12f);
            }
        short* outp = (mat == 0) ? qws : kws;
#pragma unroll
        for (int mf = 0; mf < 4; ++mf)
#pragma unroll
            for (int nf = 0; nf < 4; ++nf) {
                const int cw = (n0 & 1023) + wn + nf * 16 + l16;
                const int h = cw >> 6, d = cw & 63;
#pragma unroll
                for (int reg = 0; reg < 4; ++reg) {
                    const int s = m0 + wm + mf * 16 + quad * 4 + reg;
                    const int b = s >> 11, sl = s & (SEQ - 1);
                    outp[(((size_t)(b * NH + h) * SEQ + sl) * HD) + d] =
                        f2bf(acc[mf][nf][reg] * inv[mf][reg]);
                }
            }
    } else {
#pragma unroll
        for (int mf = 0; mf < 4; ++mf)
#pragma unroll
            for (int nf = 0; nf < 4; ++nf) {
                const int cw = (n0 & 1023) + wn + nf * 16 + l16;
                const int h = cw >> 6, d = cw & 63;
                const int s = m0 + wm + mf * 16 + quad * 4;
                const int b = s >> 11, sl = s & (SEQ - 1);
                const int pos = (sl & ~31) + ((sl & 12) >> 2) * 8 + ((sl >> 4) & 1) * 4;
                short4 o;
                o.x = f2bf(acc[mf][nf][0]); o.y = f2bf(acc[mf][nf][1]);
                o.z = f2bf(acc[mf][nf][2]); o.w = f2bf(acc[mf][nf][3]);
                *(short4*)&vperm[(((size_t)(b * NH + h) * HD + d) * SEQ) + pos] = o;
            }
    }
}

// ---------------------------------------------------------------------------
// Attention: 128-q block (2 q-sets/wave), 64-key iters, double-buffered
// K/V LDS (2x16KB = 32KB -> 4 blocks/CU) via global_load_lds + XOR swizzle.
// S^T trick (P exits MFMA in A-layout), l via ones-MFMA, raw v_exp_f32
// softmax (bounded scores), final O/l.
// Grid 1-D 512, bh = id&31 -> all q-tiles of a bh on one XCD.
// ---------------------------------------------------------------------------
__global__ __launch_bounds__(256) void attn_kernel(
    const short* __restrict__ qws, const short* __restrict__ kws,
    const short* __restrict__ vperm, float* __restrict__ out)
{
    __shared__ short Kt[2][64 * 64];   // [key][d], phys col-group ^= key&7
    __shared__ short Vt[2][64 * 64];   // [d][pos], phys col-group ^= d&7
    const int id = blockIdx.x;
    const int bh = id & 31, qt = id >> 5;
    const int b = bh >> 4, h = bh & (NH - 1);
    const size_t base = (size_t)bh * SEQ * HD;
    const int t = threadIdx.x, wave = t >> 6, lane = t & 63;
    const int quad = lane >> 4, l16 = lane & 15;

    // Q B-frags, loaded once
    bf16x8 bq[2][2];
    {
        const short* qp = qws + base + (size_t)(qt * 128 + wave * 32 + l16) * HD + quad * 8;
        bq[0][0] = *(const bf16x8*)(qp);
        bq[0][1] = *(const bf16x8*)(qp + 32);
        bq[1][0] = *(const bf16x8*)(qp + 16 * HD);
        bq[1][1] = *(const bf16x8*)(qp + 16 * HD + 32);
    }
    bf16x8 ones;
#pragma unroll
    for (int i = 0; i < 8; ++i) ones[i] = (short)0x3F80;

    // staging decode: wave covers 16 rows (2 instrs x 8 rows)
    const int krow = wave * 16 + (lane >> 3);        // + j*8
    const int kcol = ((lane & 7) ^ (krow & 7)) * 8;
    const int vl8 = lane & 7;

    // frag read offsets (buffer-relative, shorts)
    int pcK[2], pcV[2];
#pragma unroll
    for (int ks = 0; ks < 2; ++ks)
        pcK[ks] = l16 * 64 + ((ks * 32 + quad * 8) ^ ((l16 & 7) * 8));
#pragma unroll
    for (int g = 0; g < 2; ++g)
        pcV[g] = l16 * 64 + (((g * 4 + quad) ^ (l16 & 7)) * 8);

    f32x4 o_acc[2][4] = {};
    f32x4 l_acc[2] = {};

    // stage 64-key tile kt into buffer p
    auto stage = [&](int kt, int p) {
        const short* kg = kws + base + (size_t)(kt * 64 + krow) * HD + kcol;
        short* lK = &Kt[p][0] + (size_t)wave * 1024;
        short* lV = &Vt[p][0] + (size_t)wave * 1024;
#pragma unroll
        for (int j = 0; j < 2; ++j)
            gload16(kg + (size_t)j * 8 * HD, lK + j * 512);
#pragma unroll
        for (int j = 0; j < 2; ++j) {
            const int d = krow + j * 8;              // same row decode as K
            const int lg = vl8 ^ (d & 7);
            gload16(vperm + base + (size_t)d * SEQ + kt * 64 + lg * 8, lV + j * 512);
        }
    };

    stage(0, 0);
    __syncthreads();   // tile 0 resident

    for (int kt = 0; kt < SEQ / 64; ++kt) {
        const int p = kt & 1;
        if (kt + 1 < SEQ / 64) stage(kt + 1, p ^ 1);   // prefetch overlaps compute
        const short* Kp = &Kt[p][0];
        const short* Vp = &Vt[p][0];

#pragma unroll
        for (int g = 0; g < 2; ++g) {
            f32x4 st[2][2];
#pragma unroll
            for (int pp = 0; pp < 2; ++pp) {
                const int tau = 2 * g + pp;
                bf16x8 a0 = *(const bf16x8*)(Kp + pcK[0] + tau * 1024);
                bf16x8 a1 = *(const bf16x8*)(Kp + pcK[1] + tau * 1024);
#pragma unroll
                for (int qs = 0; qs < 2; ++qs) {
                    f32x4 z = {};
                    z = MFMA16(a0, bq[qs][0], z);
                    st[pp][qs] = MFMA16(a1, bq[qs][1], z);
                }
            }
            bf16x8 vf[4];
#pragma unroll
            for (int nt = 0; nt < 4; ++nt)
                vf[nt] = *(const bf16x8*)(Vp + pcV[g] + nt * 1024);
#pragma unroll
            for (int qs = 0; qs < 2; ++qs) {
                bf16x8 pa;
                unsigned* pu = (unsigned*)&pa;
                pu[0] = pack2bf(fast_exp2(st[0][qs][0]), fast_exp2(st[0][qs][1]));
                pu[1] = pack2bf(fast_exp2(st[0][qs][2]), fast_exp2(st[0][qs][3]));
                pu[2] = pack2bf(fast_exp2(st[1][qs][0]), fast_exp2(st[1][qs][1]));
                pu[3] = pack2bf(fast_exp2(st[1][qs][2]), fast_exp2(st[1][qs][3]));
                l_acc[qs] = MFMA16(pa, ones, l_acc[qs]);
#pragma unroll
                for (int nt = 0; nt < 4; ++nt)
                    o_acc[qs][nt] = MFMA16(pa, vf[nt], o_acc[qs][nt]);
            }
        }
        __syncthreads();   // drains prefetch (after compute) + guards buffer reuse
    }

    float linv[2][4];
#pragma unroll
    for (int qs = 0; qs < 2; ++qs)
#pragma unroll
        for (int r = 0; r < 4; ++r)
            linv[qs][r] = 1.0f / l_acc[qs][r];

    float* ob = out + ((size_t)b * SEQ + qt * 128 + wave * 32 + quad * 4) * EMB + h * HD + l16;
#pragma unroll
    for (int qs = 0; qs < 2; ++qs)
#pragma unroll
        for (int nt = 0; nt < 4; ++nt)
#pragma unroll
            for (int r = 0; r < 4; ++r)
                ob[(size_t)(qs * 16 + r) * EMB + nt * 16] = o_acc[qs][nt][r] * linv[qs][r];
}

extern "C" void kernel_launch(void* const* d_in, const int* in_sizes, int n_in,
                              void* d_out, int out_size, void* d_ws, size_t ws_size,
                              hipStream_t stream) {
    (void)in_sizes; (void)n_in; (void)out_size; (void)ws_size;
    const float* x  = (const float*)d_in[0];
    const float* Wq = (const float*)d_in[1];
    const float* Wk = (const float*)d_in[2];
    const float* Wv = (const float*)d_in[3];
    const float* g  = (const float*)d_in[4];
    float* out = (float*)d_out;

    const size_t per = (size_t)BAT * NH * SEQ * HD;   // 4,194,304 elems
    short* qws   = (short*)d_ws;
    short* kws   = qws + per;
    short* vperm = kws + per;                          // ws: 25.2 MB total

    // bf16 staging lives in d_out (16.8 MB; attn fully overwrites it last)
    short* xb = (short*)out;                           // 4M shorts
    short* wb = xb + (size_t)MTOT * EMB;               // 3M shorts (7M <= 8.38M cap)

    prep_kernel<<<7168, 256, 0, stream>>>(x, Wq, Wk, Wv, xb, wb);
    qkv_gemm_fast<<<(MTOT / 128) * (NTOT / 128), 256, 0, stream>>>(
        xb, wb, qws, kws, vperm, g);
    attn_kernel<<<(SEQ / 128) * BAT * NH, 256, 0, stream>>>(qws, kws, vperm, out);
}

// Round 6
// 163.934 us; speedup vs baseline: 1.0013x; 1.0013x over previous
//
#include <hip/hip_runtime.h>
#include <math.h>

#define NH 16
#define HD 64
#define SEQ 2048
#define BAT 2
#define EMB 1024
#define MTOT (BAT*SEQ)   // 4096
#define NTOT (3*EMB)     // 3072

typedef __attribute__((ext_vector_type(8))) short bf16x8;
typedef __attribute__((ext_vector_type(4))) float f32x4;

#define MFMA16(a,b,c) __builtin_amdgcn_mfma_f32_16x16x32_bf16(a,b,c,0,0,0)

__device__ inline short f2bf(float f) {
    union { float f; unsigned u; } x; x.f = f;
    unsigned r = (x.u + 0x7FFF + ((x.u >> 16) & 1)) >> 16;
    return (short)r;
}

// raw v_exp_f32 (inputs bounded to [-12,12]: no range/denorm handling needed)
__device__ inline float fast_exp2(float x) {
#if __has_builtin(__builtin_amdgcn_exp2f)
    return __builtin_amdgcn_exp2f(x);
#else
    float r; asm("v_exp_f32 %0, %1" : "=v"(r) : "v"(x)); return r;
#endif
}

// pack two rounded bf16 into one dword: 2x v_add + 1x v_perm
__device__ inline unsigned pack2bf(float a, float b) {
    union { float f; unsigned u; } x, y; x.f = a; y.f = b;
    return __builtin_amdgcn_perm(y.u + 0x8000u, x.u + 0x8000u, 0x07060302u);
}

typedef const __attribute__((address_space(1))) void* gp_t;
typedef __attribute__((address_space(3))) void* lp_t;
// async global->LDS, 16B/lane; LDS dest = wave-uniform base + lane*16
__device__ inline void gload16(const void* g, void* l) {
    __builtin_amdgcn_global_load_lds((gp_t)(uintptr_t)g, (lp_t)(uintptr_t)l, 16, 0, 0);
}

// ---------------------------------------------------------------------------
// Prep: f32 -> bf16 for X (4M) and Wq|Wk|Wv (3M) into scratch carved from d_out.
// ---------------------------------------------------------------------------
__global__ __launch_bounds__(256) void prep_kernel(
    const float* __restrict__ x, const float* __restrict__ wq,
    const float* __restrict__ wk, const float* __restrict__ wv,
    short* __restrict__ xb, short* __restrict__ wb)
{
    const size_t NX = (size_t)MTOT * EMB;
    const size_t NW = (size_t)EMB * EMB;
    const size_t i4 = ((size_t)blockIdx.x * 256 + threadIdx.x) * 4;
    float4 v; short* dst;
    if (i4 < NX) { v = *(const float4*)(x + i4); dst = xb + i4; }
    else {
        size_t j = i4 - NX;
        const float* s = (j < NW) ? wq : (j < 2 * NW) ? wk : wv;
        v = *(const float4*)(s + (j & (NW - 1)));
        dst = wb + j;
    }
    short4 o; o.x = f2bf(v.x); o.y = f2bf(v.y); o.z = f2bf(v.z); o.w = f2bf(v.w);
    *(short4*)dst = o;
}

// ---------------------------------------------------------------------------
// Fused QKV GEMM (m97 structure): 128x128 tile, BK=64, global_load_lds w=16,
// XOR-swizzled LDS. 1-D grid with XCD-locality swizzle.
// Epilogue: Q l2norm*(g*log2e), K l2norm -> [bh][s][d];
// V transposed+permuted -> vperm[bh][d][pos(s)].
// ---------------------------------------------------------------------------
__global__ __launch_bounds__(256) void qkv_gemm_fast(
    const short* __restrict__ xb, const short* __restrict__ wb,
    short* __restrict__ qws, short* __restrict__ kws, short* __restrict__ vperm,
    const float* __restrict__ gptr)
{
    __shared__ short As[128 * 64];
    __shared__ short Bs[128 * 64];
    const int id = blockIdx.x;
    const int xcd = id & 7, q8 = id >> 3;           // HW round-robins id%8 -> XCD
    const int m0 = (xcd * 4 + (q8 & 3)) * 128;      // 4 m-tiles per XCD
    const int n0 = (q8 >> 2) * 128;                 // 24 n-tiles swept per XCD
    const int t = threadIdx.x, wave = t >> 6, lane = t & 63;
    const int quad = lane >> 4, l16 = lane & 15;
    const int wm = (wave & 1) * 64, wn = (wave >> 1) * 64;

    // staging decode: instr j covers LDS rows wave*32+j*8 .. +7
    const int srow = wave * 32 + (lane >> 3);
    const int scol = ((lane & 7) ^ (srow & 7)) * 8;
    const short* ga = xb + (size_t)(m0 + srow) * EMB + scol;
    const short* gb = wb + (size_t)(n0 + srow) * EMB + scol;
    short* lA = As + (size_t)wave * 2048;
    short* lB = Bs + (size_t)wave * 2048;

    const short* Aa[2]; const short* Ba[2];
#pragma unroll
    for (int ks = 0; ks < 2; ++ks) {
        const int pc = (ks * 32 + quad * 8) ^ ((l16 & 7) * 8);
        Aa[ks] = As + (wm + l16) * 64 + pc;
        Ba[ks] = Bs + (wn + l16) * 64 + pc;
    }

    f32x4 acc[4][4] = {};

    for (int k0 = 0; k0 < EMB; k0 += 64) {
#pragma unroll
        for (int j = 0; j < 4; ++j) {
            gload16(ga + k0 + (size_t)j * 8 * EMB, lA + j * 512);
            gload16(gb + k0 + (size_t)j * 8 * EMB, lB + j * 512);
        }
        __syncthreads();
#pragma unroll
        for (int ks = 0; ks < 2; ++ks) {
            bf16x8 af[4], bfr[4];
#pragma unroll
            for (int i = 0; i < 4; ++i) af[i]  = *(const bf16x8*)(Aa[ks] + i * 1024);
#pragma unroll
            for (int i = 0; i < 4; ++i) bfr[i] = *(const bf16x8*)(Ba[ks] + i * 1024);
#pragma unroll
            for (int mf = 0; mf < 4; ++mf)
#pragma unroll
                for (int nf = 0; nf < 4; ++nf)
                    acc[mf][nf] = MFMA16(af[mf], bfr[nf], acc[mf][nf]);
        }
        __syncthreads();
    }

    // ---- epilogue ----
    const int mat = n0 >> 10;   // 0=Q,1=K,2=V (block-uniform)
    if (mat < 2) {
        const float scale = (mat == 0) ? gptr[0] * 1.4426950408889634f : 1.0f;
        float inv[4][4];
#pragma unroll
        for (int mf = 0; mf < 4; ++mf)
#pragma unroll
            for (int reg = 0; reg < 4; ++reg) {
                float ss = 0.f;
#pragma unroll
                for (int nf = 0; nf < 4; ++nf) { float v = acc[mf][nf][reg]; ss += v * v; }
                ss += __shfl_xor(ss, 1, 16);
                ss += __shfl_xor(ss, 2, 16);
                ss += __shfl_xor(ss, 4, 16);
                ss += __shfl_xor(ss, 8, 16);
                inv[mf][reg] = scale / fmaxf(sqrtf(ss), 1e-12f);
            }
        short* outp = (mat == 0) ? qws : kws;
#pragma unroll
        for (int mf = 0; mf < 4; ++mf)
#pragma unroll
            for (int nf = 0; nf < 4; ++nf) {
                const int cw = (n0 & 1023) + wn + nf * 16 + l16;
                const int h = cw >> 6, d = cw & 63;
#pragma unroll
                for (int reg = 0; reg < 4; ++reg) {
                    const int s = m0 + wm + mf * 16 + quad * 4 + reg;
                    const int b = s >> 11, sl = s & (SEQ - 1);
                    outp[(((size_t)(b * NH + h) * SEQ + sl) * HD) + d] =
                        f2bf(acc[mf][nf][reg] * inv[mf][reg]);
                }
            }
    } else {
#pragma unroll
        for (int mf = 0; mf < 4; ++mf)
#pragma unroll
            for (int nf = 0; nf < 4; ++nf) {
                const int cw = (n0 & 1023) + wn + nf * 16 + l16;
                const int h = cw >> 6, d = cw & 63;
                const int s = m0 + wm + mf * 16 + quad * 4;
                const int b = s >> 11, sl = s & (SEQ - 1);
                const int pos = (sl & ~31) + ((sl & 12) >> 2) * 8 + ((sl >> 4) & 1) * 4;
                short4 o;
                o.x = f2bf(acc[mf][nf][0]); o.y = f2bf(acc[mf][nf][1]);
                o.z = f2bf(acc[mf][nf][2]); o.w = f2bf(acc[mf][nf][3]);
                *(short4*)&vperm[(((size_t)(b * NH + h) * HD + d) * SEQ) + pos] = o;
            }
    }
}

// ---------------------------------------------------------------------------
// Attention: 64-q block (16 q/wave), 64-key iters, double-buffered K/V LDS
// (2x16KB = 32KB) via global_load_lds + XOR swizzle. Grid 1024 = 4 blocks/CU
// (the round-5 bug: 512 blocks capped occupancy at 2 blocks/CU regardless of
// LDS). S^T trick (P exits MFMA in A-layout), l via ones-MFMA, raw v_exp_f32
// softmax (bounded scores), final O/l.
// Grid 1-D, bh = id&31 -> all q-tiles of a bh on one XCD (KV L2-resident).
// ---------------------------------------------------------------------------
__global__ __launch_bounds__(256, 4) void attn_kernel(
    const short* __restrict__ qws, const short* __restrict__ kws,
    const short* __restrict__ vperm, float* __restrict__ out)
{
    __shared__ short Kt[2][64 * 64];   // [key][d], phys col-group ^= key&7
    __shared__ short Vt[2][64 * 64];   // [d][pos], phys col-group ^= d&7
    const int id = blockIdx.x;
    const int bh = id & 31, qt = id >> 5;            // qt 0..31
    const int b = bh >> 4, h = bh & (NH - 1);
    const size_t base = (size_t)bh * SEQ * HD;
    const int t = threadIdx.x, wave = t >> 6, lane = t & 63;
    const int quad = lane >> 4, l16 = lane & 15;

    // Q B-frags, loaded once (16 q rows per wave)
    bf16x8 bq[2];
    {
        const short* qp = qws + base + (size_t)(qt * 64 + wave * 16 + l16) * HD + quad * 8;
        bq[0] = *(const bf16x8*)(qp);
        bq[1] = *(const bf16x8*)(qp + 32);
    }
    bf16x8 ones;
#pragma unroll
    for (int i = 0; i < 8; ++i) ones[i] = (short)0x3F80;

    // staging decode: wave covers 16 rows (2 instrs x 8 rows)
    const int krow = wave * 16 + (lane >> 3);        // + j*8
    const int kcol = ((lane & 7) ^ (krow & 7)) * 8;
    const int vl8 = lane & 7;

    // frag read offsets (buffer-relative, shorts)
    int pcK[2], pcV[2];
#pragma unroll
    for (int ks = 0; ks < 2; ++ks)
        pcK[ks] = l16 * 64 + ((ks * 32 + quad * 8) ^ ((l16 & 7) * 8));
#pragma unroll
    for (int g = 0; g < 2; ++g)
        pcV[g] = l16 * 64 + (((g * 4 + quad) ^ (l16 & 7)) * 8);

    f32x4 o_acc[4] = {};
    f32x4 l_acc = {};

    // stage 64-key tile kt into buffer p
    auto stage = [&](int kt, int p) {
        const short* kg = kws + base + (size_t)(kt * 64 + krow) * HD + kcol;
        short* lK = &Kt[p][0] + (size_t)wave * 1024;
        short* lV = &Vt[p][0] + (size_t)wave * 1024;
#pragma unroll
        for (int j = 0; j < 2; ++j)
            gload16(kg + (size_t)j * 8 * HD, lK + j * 512);
#pragma unroll
        for (int j = 0; j < 2; ++j) {
            const int d = krow + j * 8;              // same row decode as K
            const int lg = vl8 ^ (d & 7);
            gload16(vperm + base + (size_t)d * SEQ + kt * 64 + lg * 8, lV + j * 512);
        }
    };

    stage(0, 0);
    __syncthreads();   // tile 0 resident

    for (int kt = 0; kt < SEQ / 64; ++kt) {
        const int p = kt & 1;
        if (kt + 1 < SEQ / 64) stage(kt + 1, p ^ 1);   // prefetch overlaps compute
        const short* Kp = &Kt[p][0];
        const short* Vp = &Vt[p][0];

#pragma unroll
        for (int g = 0; g < 2; ++g) {
            f32x4 st[2];
#pragma unroll
            for (int pp = 0; pp < 2; ++pp) {
                const int tau = 2 * g + pp;
                bf16x8 a0 = *(const bf16x8*)(Kp + pcK[0] + tau * 1024);
                bf16x8 a1 = *(const bf16x8*)(Kp + pcK[1] + tau * 1024);
                f32x4 z = {};
                z = MFMA16(a0, bq[0], z);
                st[pp] = MFMA16(a1, bq[1], z);
            }
            bf16x8 vf[4];
#pragma unroll
            for (int nt = 0; nt < 4; ++nt)
                vf[nt] = *(const bf16x8*)(Vp + pcV[g] + nt * 1024);

            bf16x8 pa;
            unsigned* pu = (unsigned*)&pa;
            pu[0] = pack2bf(fast_exp2(st[0][0]), fast_exp2(st[0][1]));
            pu[1] = pack2bf(fast_exp2(st[0][2]), fast_exp2(st[0][3]));
            pu[2] = pack2bf(fast_exp2(st[1][0]), fast_exp2(st[1][1]));
            pu[3] = pack2bf(fast_exp2(st[1][2]), fast_exp2(st[1][3]));
            l_acc = MFMA16(pa, ones, l_acc);
#pragma unroll
            for (int nt = 0; nt < 4; ++nt)
                o_acc[nt] = MFMA16(pa, vf[nt], o_acc[nt]);
        }
        __syncthreads();   // drains prefetch (after compute) + guards buffer reuse
    }

    float linv[4];
#pragma unroll
    for (int r = 0; r < 4; ++r)
        linv[r] = 1.0f / l_acc[r];

    float* ob = out + ((size_t)b * SEQ + qt * 64 + wave * 16 + quad * 4) * EMB + h * HD + l16;
#pragma unroll
    for (int nt = 0; nt < 4; ++nt)
#pragma unroll
        for (int r = 0; r < 4; ++r)
            ob[(size_t)r * EMB + nt * 16] = o_acc[nt][r] * linv[r];
}

extern "C" void kernel_launch(void* const* d_in, const int* in_sizes, int n_in,
                              void* d_out, int out_size, void* d_ws, size_t ws_size,
                              hipStream_t stream) {
    (void)in_sizes; (void)n_in; (void)out_size; (void)ws_size;
    const float* x  = (const float*)d_in[0];
    const float* Wq = (const float*)d_in[1];
    const float* Wk = (const float*)d_in[2];
    const float* Wv = (const float*)d_in[3];
    const float* g  = (const float*)d_in[4];
    float* out = (float*)d_out;

    const size_t per = (size_t)BAT * NH * SEQ * HD;   // 4,194,304 elems
    short* qws   = (short*)d_ws;
    short* kws   = qws + per;
    short* vperm = kws + per;                          // ws: 25.2 MB total

    // bf16 staging lives in d_out (16.8 MB; attn fully overwrites it last)
    short* xb = (short*)out;                           // 4M shorts
    short* wb = xb + (size_t)MTOT * EMB;               // 3M shorts (7M <= 8.38M cap)

    prep_kernel<<<7168, 256, 0, stream>>>(x, Wq, Wk, Wv, xb, wb);
    qkv_gemm_fast<<<(MTOT / 128) * (NTOT / 128), 256, 0, stream>>>(
        xb, wb, qws, kws, vperm, g);
    attn_kernel<<<(SEQ / 64) * BAT * NH, 256, 0, stream>>>(qws, kws, vperm, out);
}